// Round 4
// baseline (244.982 us; speedup 1.0000x reference)
//
#include <hip/hip_runtime.h>
#include <hip/hip_bf16.h>

constexpr int NF = 128;   // H*D == IN_F == OUT_F
// NOTE (hard-won): ALL tensor inputs and the output are FP32. Reading them as
// bf16 was the root cause of every mystery failure in rounds 1-13.
// fs is *stored* bf16 (halves gather bytes). fd is staged fp32 in d_out.
// LESSON r17: cooperative grid.sync costs ~100 us/sync at 1024 blocks.
// R18: hist fused into GEMM. R19: 64-row tiles. R20: prep_kernel pre-converts
// W to bf16 fragment order; 32-row tiles. gemm_hist stuck at ~59 us though —
// MfmaUtil 2%, VALU 6%: waves waiting on the hist atomicAdd-with-return chain.
// R21: edge pipeline rework:
//   - hist = fire-and-forget atomicAdd (latency hides under same-block GEMM),
//     pack[] eliminated.
//   - rank computed in scatter via cursor[] (2nd rowptr copy), int4 edge loads
//     give 4 independent atomic chains per thread.
//   - scan1+scan23 merged into ONE decoupled-lookback scan (wave-parallel
//     64-wide lookback, flag|value packed in a single atomic word).
//   Dispatches 6 -> 5 (launch gap ~10us each per G11).

using bf16x8 = __attribute__((ext_vector_type(8))) short;
using f32x4v = __attribute__((ext_vector_type(4))) float;

__device__ __forceinline__ unsigned short f2bs(float f) {
    return __builtin_bit_cast(unsigned short, __float2bfloat16(f));
}
__device__ __forceinline__ void unpack8(float4 raw, float* a) {
    unsigned u0 = __float_as_uint(raw.x);
    unsigned u1 = __float_as_uint(raw.y);
    unsigned u2 = __float_as_uint(raw.z);
    unsigned u3 = __float_as_uint(raw.w);
    a[0] = __uint_as_float(u0 << 16);
    a[1] = __uint_as_float(u0 & 0xffff0000u);
    a[2] = __uint_as_float(u1 << 16);
    a[3] = __uint_as_float(u1 & 0xffff0000u);
    a[4] = __uint_as_float(u2 << 16);
    a[5] = __uint_as_float(u2 & 0xffff0000u);
    a[6] = __uint_as_float(u3 << 16);
    a[7] = __uint_as_float(u3 & 0xffff0000u);
}

// Name insurance: harmless, never launched with real work.
__global__ void GraphAttnLayer_70196945486348_kernel() {}

// ---------------------------------------------------------------------------
// K0: prep — zero cnt + scan state, transpose/convert W to bf16 fragment
//     layout Wb[col][k], col 0..127 = Wsrc, 128..255 = Wdst.
// ---------------------------------------------------------------------------
__global__ __launch_bounds__(256) void prep_kernel(
    const float* __restrict__ Wsrc, const float* __restrict__ Wdst,
    unsigned short* __restrict__ Wb,   // [256][128] bf16
    int* __restrict__ cnt, int* __restrict__ state, int N, int NB)
{
    int i = blockIdx.x * 256 + threadIdx.x;
    if (i < N) cnt[i] = 0;
    if (i < NB) state[i] = 0;
    if (i < 256 * NF) {
        int k   = i >> 8;      // 0..127
        int col = i & 255;     // 0..255
        float v = (col < 128) ? Wsrc[k * NF + col] : Wdst[k * NF + (col - 128)];
        Wb[col * NF + k] = f2bs(v);
    }
}

// ---------------------------------------------------------------------------
// K1: fused MFMA projection GEMM + fire-and-forget edge histogram.
//     Grid = NGB = ceil(N/32) = 1563. Every block: 512-edge hist chunk
//     (no return value used -> latency hides under the GEMM) + 32-row tile.
// ---------------------------------------------------------------------------
__global__ __launch_bounds__(256) void gemm_hist_kernel(
    const float* __restrict__ x,
    const unsigned short* __restrict__ Wb,  // [256][128] bf16 fragment-order
    const float* __restrict__ bsrc, const float* __restrict__ bdst,
    unsigned short* __restrict__ fs,   // [N][128] bf16
    float* __restrict__ fd,            // [N][128] fp32 (d_out)
    const int* __restrict__ dst,
    int* __restrict__ cnt,
    int N, int E)
{
    {   // fire-and-forget hist: 2 edges/thread, independent, no return use.
        int e0 = blockIdx.x * 512 + threadIdx.x;
        int e1 = e0 + 256;
        int d0 = (e0 < E) ? dst[e0] : -1;
        int d1 = (e1 < E) ? dst[e1] : -1;
        if (d0 >= 0) atomicAdd(&cnt[d0], 1);
        if (d1 >= 0) atomicAdd(&cnt[d1], 1);
    }

    const int lane = threadIdx.x & 63;
    const int wave = threadIdx.x >> 6;
    const int m_base = blockIdx.x * 32;
    const int lm = lane & 15;
    const int kq = (lane >> 4) * 8;

    bf16x8 bfrag[4][4];
    float bias[4];
#pragma unroll
    for (int c = 0; c < 4; ++c) {
        int col = wave * 64 + c * 16 + lm;  // 0..255
        bias[c] = (col < 128) ? bsrc[col] : bdst[col - 128];
#pragma unroll
        for (int s = 0; s < 4; ++s)
            bfrag[c][s] = *(const bf16x8*)(Wb + col * NF + s * 32 + kq);
    }

    for (int r = 0; r < 2; ++r) {
        int m0 = m_base + r * 16;
        if (m0 >= N) break;
        int row = m0 + lm;
        if (row >= N) row = N - 1;
        bf16x8 afrag[4];
#pragma unroll
        for (int s = 0; s < 4; ++s) {
            const float4* xp = (const float4*)(x + (size_t)row * NF + s * 32 + kq);
            float4 xa = xp[0], xb = xp[1];
            afrag[s][0] = (short)f2bs(xa.x);
            afrag[s][1] = (short)f2bs(xa.y);
            afrag[s][2] = (short)f2bs(xa.z);
            afrag[s][3] = (short)f2bs(xa.w);
            afrag[s][4] = (short)f2bs(xb.x);
            afrag[s][5] = (short)f2bs(xb.y);
            afrag[s][6] = (short)f2bs(xb.z);
            afrag[s][7] = (short)f2bs(xb.w);
        }
#pragma unroll
        for (int c = 0; c < 4; ++c) {
            f32x4v acc = {0.f, 0.f, 0.f, 0.f};
#pragma unroll
            for (int s = 0; s < 4; ++s)
                acc = __builtin_amdgcn_mfma_f32_16x16x32_bf16(afrag[s], bfrag[c][s], acc, 0, 0, 0);
            int col = wave * 64 + c * 16 + lm;
            int cc = col & 127;
#pragma unroll
            for (int rr = 0; rr < 4; ++rr) {
                int rowd = m0 + (lane >> 4) * 4 + rr;
                if (rowd < N) {
                    float v = acc[rr] + bias[c];
                    if (col < 128) fs[(size_t)rowd * NF + cc] = f2bs(v);
                    else           fd[(size_t)rowd * NF + cc] = v;
                }
            }
        }
    }
}

// ---------------------------------------------------------------------------
// K2: single-pass decoupled-lookback scan of cnt -> rowptr (+cursor copy).
//     state[b]: packed (flag<<30)|value. flag 0=empty, 1=aggregate, 2=prefix.
//     Values <= E = 800000 < 2^30. Wave 0 of each block does a 64-wide
//     parallel lookback. All NB=196 blocks co-resident on 256 CUs.
// ---------------------------------------------------------------------------
__global__ __launch_bounds__(256) void scan_kernel(
    const int* __restrict__ cnt, int* __restrict__ rowptr,
    int* __restrict__ cursor, int* __restrict__ state, int N, int E)
{
    int b = blockIdx.x, t = threadIdx.x;
    int i = b * 256 + t;
    int v = (i < N) ? cnt[i] : 0;

    __shared__ int arr[256];
    __shared__ int s_bofs;
    arr[t] = v;
    __syncthreads();
    for (int off = 1; off < 256; off <<= 1) {
        int u = (t >= off) ? arr[t - off] : 0;
        __syncthreads();
        arr[t] += u;
        __syncthreads();
    }
    int total = arr[255];

    if (t < 64) {
        if (t == 0) {
            int word = ((b == 0 ? 2 : 1) << 30) | total;
            atomicExch(&state[b], word);
        }
        int bofs = 0;
        if (b > 0) {
            int base = b;
            for (;;) {
                int j = base - 1 - t;
                int sv = 0, f = 1;
                if (j >= 0) {
                    sv = atomicAdd(&state[j], 0);   // atomic load
                    f = ((unsigned)sv) >> 30;
                }
                unsigned long long notready = __ballot(f == 0);
                if (notready) continue;             // spin until window ready
                unsigned long long has2 = __ballot(f == 2);
                if (has2) {
                    int k = (int)(__ffsll((unsigned long long)has2) - 1);
                    int val = (t <= k) ? (sv & 0x3FFFFFFF) : 0;
#pragma unroll
                    for (int off = 32; off; off >>= 1) val += __shfl_xor(val, off);
                    bofs += val;
                    break;
                } else {
                    int val = (j >= 0) ? (sv & 0x3FFFFFFF) : 0;
#pragma unroll
                    for (int off = 32; off; off >>= 1) val += __shfl_xor(val, off);
                    bofs += val;
                    base -= 64;
                }
            }
            if (t == 0) atomicExch(&state[b], (2 << 30) | (bofs + total));
        }
        if (t == 0) s_bofs = bofs;
    }
    __syncthreads();
    int bofs = s_bofs;
    int excl = arr[t] - v + bofs;
    if (i < N) { rowptr[i] = excl; cursor[i] = excl; }
    if (i == 0) rowptr[N] = E;
}

// ---------------------------------------------------------------------------
// K3: scatter with rank-on-the-fly: slot = atomicAdd(&cursor[dst], 1).
//     int4 loads -> 4 independent atomic chains per thread.
// ---------------------------------------------------------------------------
__global__ __launch_bounds__(256) void scatter_kernel(
    const int* __restrict__ dst, const int* __restrict__ src,
    int* __restrict__ cursor, int* __restrict__ src_sorted, int E)
{
    int idx = blockIdx.x * 256 + threadIdx.x;
    int e0 = idx * 4;
    if (e0 + 3 < E) {
        int4 d = *(const int4*)(dst + e0);
        int4 s = *(const int4*)(src + e0);
        int s0 = atomicAdd(&cursor[d.x], 1);
        int s1 = atomicAdd(&cursor[d.y], 1);
        int s2 = atomicAdd(&cursor[d.z], 1);
        int s3 = atomicAdd(&cursor[d.w], 1);
        src_sorted[s0] = s.x;
        src_sorted[s1] = s.y;
        src_sorted[s2] = s.z;
        src_sorted[s3] = s.w;
    } else {
        for (int e = e0; e < E; ++e) {
            int sl = atomicAdd(&cursor[dst[e]], 1);
            src_sorted[sl] = src[e];
        }
    }
}

// ---------------------------------------------------------------------------
// K5 v4: node-centric fused softmax-attention + bias + LN + ELU.
//     (r15/r16 passing version, byte-identical.)
// ---------------------------------------------------------------------------
__global__ __launch_bounds__(256) void node_kernel(
    const float4* __restrict__ fsq,      // fs as [N][16] float4 (8 bf16 each)
    const int* __restrict__ rowptr, const int* __restrict__ src_sorted,
    const float4* __restrict__ attn4,    // [32] float4
    const float4* __restrict__ obias4,
    const float4* __restrict__ lnw4,
    const float4* __restrict__ lnb4,
    float4* __restrict__ out4, int N)    // d_out as [N][32] float4
{
    int lane = threadIdx.x & 63;
    int es = lane >> 4;       // edge slot
    int g  = lane & 15;       // dim group: dims g*8 .. g*8+7
    int n = blockIdx.x * 4 + (threadIdx.x >> 6);
    if (n >= N) return;

    float4 fda = out4[(size_t)n * 32 + g * 2];
    float4 fdb = out4[(size_t)n * 32 + g * 2 + 1];
    float4 ava = attn4[g * 2];
    float4 avb = attn4[g * 2 + 1];
    float fd[8] = {fda.x, fda.y, fda.z, fda.w, fdb.x, fdb.y, fdb.z, fdb.w};
    float av[8] = {ava.x, ava.y, ava.z, ava.w, avb.x, avb.y, avb.z, avb.w};

    int beg = rowptr[n], end = rowptr[n + 1];
    float l = 0.f;
    float ac[8] = {0.f, 0.f, 0.f, 0.f, 0.f, 0.f, 0.f, 0.f};

    for (int j = beg; j < end; j += 4) {
        int idx = j + es;
        bool valid = idx < end;
        int s = src_sorted[valid ? idx : (end - 1)];
        float4 raw = fsq[(size_t)s * 16 + g];
        float a[8];
        unpack8(raw, a);
        float p = 0.f;
#pragma unroll
        for (int d = 0; d < 8; ++d) {
            float t = a[d] + fd[d];
            t = fmaxf(t, 0.2f * t);          // leaky_relu
            p += av[d] * t;
        }
        p += __shfl_xor(p, 1);               // head reduce (4 lanes/head)
        p += __shfl_xor(p, 2);
        float e = valid ? __expf(p) : 0.f;
        l += e;
#pragma unroll
        for (int d = 0; d < 8; ++d) ac[d] += e * a[d];
    }

    l += __shfl_xor(l, 16);
    l += __shfl_xor(l, 32);
#pragma unroll
    for (int d = 0; d < 8; ++d) {
        ac[d] += __shfl_xor(ac[d], 16);
        ac[d] += __shfl_xor(ac[d], 32);
    }

    float rl = (l > 0.f) ? (1.f / l) : 0.f;
    float4 oba = obias4[g * 2];
    float4 obb = obias4[g * 2 + 1];
    float ob[8] = {oba.x, oba.y, oba.z, oba.w, obb.x, obb.y, obb.z, obb.w};
    float h[8];
    float s1 = 0.f, s2 = 0.f;
#pragma unroll
    for (int d = 0; d < 8; ++d) {
        h[d] = ac[d] * rl + ob[d];
        s1 += h[d];
        s2 += h[d] * h[d];
    }
    s1 += __shfl_xor(s1, 1); s2 += __shfl_xor(s2, 1);
    s1 += __shfl_xor(s1, 2); s2 += __shfl_xor(s2, 2);
    s1 += __shfl_xor(s1, 4); s2 += __shfl_xor(s2, 4);
    s1 += __shfl_xor(s1, 8); s2 += __shfl_xor(s2, 8);

    float u = s1 * (1.f / NF);
    float var = s2 * (1.f / NF) - u * u;
    float rstd = rsqrtf(fmaxf(var, 0.f) + 1e-12f);
    float4 gwa = lnw4[g * 2], gwb = lnw4[g * 2 + 1];
    float4 gba = lnb4[g * 2], gbb = lnb4[g * 2 + 1];
    float gw[8] = {gwa.x, gwa.y, gwa.z, gwa.w, gwb.x, gwb.y, gwb.z, gwb.w};
    float gb[8] = {gba.x, gba.y, gba.z, gba.w, gbb.x, gbb.y, gbb.z, gbb.w};
    float z[8];
#pragma unroll
    for (int d = 0; d < 8; ++d) {
        float y = gw[d] * ((h[d] - u) * rstd) + gb[d];
        z[d] = (y > 0.f) ? y : (__expf(y) - 1.f);   // ELU alpha=1
    }
    if (es == 0) {
        out4[(size_t)n * 32 + g * 2]     = make_float4(z[0], z[1], z[2], z[3]);
        out4[(size_t)n * 32 + g * 2 + 1] = make_float4(z[4], z[5], z[6], z[7]);
    }
}

// ---------------------------------------------------------------------------
extern "C" void kernel_launch(void* const* d_in, const int* in_sizes, int n_in,
                              void* d_out, int out_size, void* d_ws, size_t ws_size,
                              hipStream_t stream)
{
    const float* x    = (const float*)d_in[0];
    const float* Wsrc = (const float*)d_in[1];
    const float* bsrc = (const float*)d_in[2];
    const float* Wdst = (const float*)d_in[3];
    const float* bdst = (const float*)d_in[4];
    const float4* attn4 = (const float4*)d_in[5];
    const float4* obias4= (const float4*)d_in[6];
    const float4* lnw4  = (const float4*)d_in[7];
    const float4* lnb4  = (const float4*)d_in[8];
    const int* src = (const int*)d_in[9];
    const int* dst = (const int*)d_in[10];
    int N = in_sizes[0] / NF;
    int E = in_sizes[9];
    int NB = (N + 255) / 256;   // 196 for N = 50000

    // workspace (~16.6 MB): cnt N | rowptr N+1 | cursor N | state NB |
    //                       srcs E | Wb 32768 bf16 | fs N*128 bf16
    int* cnt = (int*)d_ws;                       // N
    int* rowptr = cnt + N;                       // N+1
    int* cursor = rowptr + (N + 1);              // N
    int* state = cursor + N;                     // NB
    int* srcs = state + NB;                      // E
    unsigned short* Wb = (unsigned short*)(srcs + E);    // [256][128] bf16
    unsigned short* fs = Wb + 256 * NF;          // [N][128] bf16

    int NGB = (N + 31) / 32;                     // 1563; hist coverage 512/blk

    prep_kernel<<<NB, 256, 0, stream>>>(Wsrc, Wdst, Wb, cnt, state, N, NB);
    gemm_hist_kernel<<<NGB, 256, 0, stream>>>(
        x, Wb, bsrc, bdst, fs, (float*)d_out, dst, cnt, N, E);
    scan_kernel<<<NB, 256, 0, stream>>>(cnt, rowptr, cursor, state, N, E);
    scatter_kernel<<<(E / 4 + 255) / 256, 256, 0, stream>>>(dst, src, cursor, srcs, E);
    node_kernel<<<(N + 3) / 4, 256, 0, stream>>>(
        (const float4*)fs, rowptr, srcs, attn4, obias4, lnw4, lnb4,
        (float4*)d_out, N);
}

// Round 6
// 212.649 us; speedup vs baseline: 1.1521x; 1.1521x over previous
//
#include <hip/hip_runtime.h>
#include <hip/hip_bf16.h>

constexpr int NF = 128;   // H*D == IN_F == OUT_F
// NOTE (hard-won): ALL tensor inputs and the output are FP32. Reading them as
// bf16 was the root cause of every mystery failure in rounds 1-13.
// fs is *stored* bf16 (halves gather bytes). fd is staged fp32 in d_out.
// LESSON r17: cooperative grid.sync costs ~100 us/sync at 1024 blocks.
// R18: hist fused into GEMM. R19/R20: tile shrink + prep-converted W.
// R21 (REGRESSED 245us): cursor-atomic scatter = naked atomicAdd-return chain
//   with nothing to hide it. ALSO LEARNED: gemm_hist time is NOT the hist
//   atomic (59us with or without it) — suspect small-segment store epilogue.
// R22: revert to R20 pipeline (rank+pack in hist, atomic-free scatter), keep
//   R21's validated single-pass lookback scan (replaces scan1+scan23), int4
//   ILP in scatter. 5 dispatches. gemm_hist/node byte-identical to R20.
// R23: identical resubmit — R22 bench was GPUAcquisitionTimeout (infra).

using bf16x8 = __attribute__((ext_vector_type(8))) short;
using f32x4v = __attribute__((ext_vector_type(4))) float;

__device__ __forceinline__ unsigned short f2bs(float f) {
    return __builtin_bit_cast(unsigned short, __float2bfloat16(f));
}
__device__ __forceinline__ void unpack8(float4 raw, float* a) {
    unsigned u0 = __float_as_uint(raw.x);
    unsigned u1 = __float_as_uint(raw.y);
    unsigned u2 = __float_as_uint(raw.z);
    unsigned u3 = __float_as_uint(raw.w);
    a[0] = __uint_as_float(u0 << 16);
    a[1] = __uint_as_float(u0 & 0xffff0000u);
    a[2] = __uint_as_float(u1 << 16);
    a[3] = __uint_as_float(u1 & 0xffff0000u);
    a[4] = __uint_as_float(u2 << 16);
    a[5] = __uint_as_float(u2 & 0xffff0000u);
    a[6] = __uint_as_float(u3 << 16);
    a[7] = __uint_as_float(u3 & 0xffff0000u);
}

// Name insurance: harmless, never launched with real work.
__global__ void GraphAttnLayer_70196945486348_kernel() {}

// ---------------------------------------------------------------------------
// K0: prep — zero cnt + scan state, transpose/convert W to bf16 fragment
//     layout Wb[col][k], col 0..127 = Wsrc, 128..255 = Wdst.
// ---------------------------------------------------------------------------
__global__ __launch_bounds__(256) void prep_kernel(
    const float* __restrict__ Wsrc, const float* __restrict__ Wdst,
    unsigned short* __restrict__ Wb,   // [256][128] bf16
    int* __restrict__ cnt, int* __restrict__ state, int N, int NB)
{
    int i = blockIdx.x * 256 + threadIdx.x;
    if (i < N) cnt[i] = 0;
    if (i < NB) state[i] = 0;
    if (i < 256 * NF) {
        int k   = i >> 8;      // 0..127
        int col = i & 255;     // 0..255
        float v = (col < 128) ? Wsrc[k * NF + col] : Wdst[k * NF + (col - 128)];
        Wb[col * NF + k] = f2bs(v);
    }
}

// ---------------------------------------------------------------------------
// K1: fused MFMA projection GEMM + edge histogram (rank + pack, R20 style).
//     Grid = ceil(E/256) = 3125 blocks. ALL blocks do a 256-edge hist chunk.
//     Blocks < NGB (=ceil(N/32)=1563) additionally compute a 32-row GEMM tile.
// ---------------------------------------------------------------------------
__global__ __launch_bounds__(256) void gemm_hist_kernel(
    const float* __restrict__ x,
    const unsigned short* __restrict__ Wb,  // [256][128] bf16 fragment-order
    const float* __restrict__ bsrc, const float* __restrict__ bdst,
    unsigned short* __restrict__ fs,   // [N][128] bf16
    float* __restrict__ fd,            // [N][128] fp32 (d_out)
    const int* __restrict__ src, const int* __restrict__ dst,
    int* __restrict__ cnt, int* __restrict__ pack,
    int N, int E, int NGB)
{
    {   // folded hist chunk: rank = old count; pack (rank<<17)|src.
        int e = blockIdx.x * 256 + threadIdx.x;
        if (e < E) {
            int r = atomicAdd(&cnt[dst[e]], 1);
            pack[e] = (r << 17) | src[e];
        }
    }
    if (blockIdx.x >= NGB) return;

    const int lane = threadIdx.x & 63;
    const int wave = threadIdx.x >> 6;
    const int m_base = blockIdx.x * 32;
    const int lm = lane & 15;
    const int kq = (lane >> 4) * 8;

    bf16x8 bfrag[4][4];
    float bias[4];
#pragma unroll
    for (int c = 0; c < 4; ++c) {
        int col = wave * 64 + c * 16 + lm;  // 0..255
        bias[c] = (col < 128) ? bsrc[col] : bdst[col - 128];
#pragma unroll
        for (int s = 0; s < 4; ++s)
            bfrag[c][s] = *(const bf16x8*)(Wb + col * NF + s * 32 + kq);
    }

    for (int r = 0; r < 2; ++r) {
        int m0 = m_base + r * 16;
        if (m0 >= N) break;
        int row = m0 + lm;
        if (row >= N) row = N - 1;
        bf16x8 afrag[4];
#pragma unroll
        for (int s = 0; s < 4; ++s) {
            const float4* xp = (const float4*)(x + (size_t)row * NF + s * 32 + kq);
            float4 xa = xp[0], xb = xp[1];
            afrag[s][0] = (short)f2bs(xa.x);
            afrag[s][1] = (short)f2bs(xa.y);
            afrag[s][2] = (short)f2bs(xa.z);
            afrag[s][3] = (short)f2bs(xa.w);
            afrag[s][4] = (short)f2bs(xb.x);
            afrag[s][5] = (short)f2bs(xb.y);
            afrag[s][6] = (short)f2bs(xb.z);
            afrag[s][7] = (short)f2bs(xb.w);
        }
#pragma unroll
        for (int c = 0; c < 4; ++c) {
            f32x4v acc = {0.f, 0.f, 0.f, 0.f};
#pragma unroll
            for (int s = 0; s < 4; ++s)
                acc = __builtin_amdgcn_mfma_f32_16x16x32_bf16(afrag[s], bfrag[c][s], acc, 0, 0, 0);
            int col = wave * 64 + c * 16 + lm;
            int cc = col & 127;
#pragma unroll
            for (int rr = 0; rr < 4; ++rr) {
                int rowd = m0 + (lane >> 4) * 4 + rr;
                if (rowd < N) {
                    float v = acc[rr] + bias[c];
                    if (col < 128) fs[(size_t)rowd * NF + cc] = f2bs(v);
                    else           fd[(size_t)rowd * NF + cc] = v;
                }
            }
        }
    }
}

// ---------------------------------------------------------------------------
// K2: single-pass decoupled-lookback scan of cnt -> rowptr (validated R21).
//     state[b]: packed (flag<<30)|value. flag 0=empty, 1=aggregate, 2=prefix.
//     Values <= E = 800000 < 2^30. Wave 0 does a 64-wide parallel lookback.
// ---------------------------------------------------------------------------
__global__ __launch_bounds__(256) void scan_kernel(
    const int* __restrict__ cnt, int* __restrict__ rowptr,
    int* __restrict__ state, int N, int E)
{
    int b = blockIdx.x, t = threadIdx.x;
    int i = b * 256 + t;
    int v = (i < N) ? cnt[i] : 0;

    __shared__ int arr[256];
    __shared__ int s_bofs;
    arr[t] = v;
    __syncthreads();
    for (int off = 1; off < 256; off <<= 1) {
        int u = (t >= off) ? arr[t - off] : 0;
        __syncthreads();
        arr[t] += u;
        __syncthreads();
    }
    int total = arr[255];

    if (t < 64) {
        if (t == 0) {
            int word = ((b == 0 ? 2 : 1) << 30) | total;
            atomicExch(&state[b], word);
        }
        int bofs = 0;
        if (b > 0) {
            int base = b;
            for (;;) {
                int j = base - 1 - t;
                int sv = 0, f = 1;
                if (j >= 0) {
                    sv = atomicAdd(&state[j], 0);   // atomic load
                    f = ((unsigned)sv) >> 30;
                }
                unsigned long long notready = __ballot(f == 0);
                if (notready) continue;             // spin until window ready
                unsigned long long has2 = __ballot(f == 2);
                if (has2) {
                    int k = (int)(__ffsll((unsigned long long)has2) - 1);
                    int val = (t <= k) ? (sv & 0x3FFFFFFF) : 0;
#pragma unroll
                    for (int off = 32; off; off >>= 1) val += __shfl_xor(val, off);
                    bofs += val;
                    break;
                } else {
                    int val = (j >= 0) ? (sv & 0x3FFFFFFF) : 0;
#pragma unroll
                    for (int off = 32; off; off >>= 1) val += __shfl_xor(val, off);
                    bofs += val;
                    base -= 64;
                }
            }
            if (t == 0) atomicExch(&state[b], (2 << 30) | (bofs + total));
        }
        if (t == 0) s_bofs = bofs;
    }
    __syncthreads();
    int bofs = s_bofs;
    int excl = arr[t] - v + bofs;
    if (i < N) rowptr[i] = excl;
    if (i == 0) rowptr[N] = E;
}

// ---------------------------------------------------------------------------
// K3: scatter (atomic-free): slot = rowptr[dst] + rank; int4 = 4 edges/thread.
// ---------------------------------------------------------------------------
__global__ __launch_bounds__(256) void scatter_kernel(
    const int* __restrict__ dst, const int* __restrict__ pack,
    const int* __restrict__ rowptr, int* __restrict__ src_sorted, int E)
{
    int idx = blockIdx.x * 256 + threadIdx.x;
    int e0 = idx * 4;
    if (e0 + 3 < E) {
        int4 d = *(const int4*)(dst + e0);
        int4 p = *(const int4*)(pack + e0);
        src_sorted[rowptr[d.x] + (p.x >> 17)] = p.x & 0x1FFFF;
        src_sorted[rowptr[d.y] + (p.y >> 17)] = p.y & 0x1FFFF;
        src_sorted[rowptr[d.z] + (p.z >> 17)] = p.z & 0x1FFFF;
        src_sorted[rowptr[d.w] + (p.w >> 17)] = p.w & 0x1FFFF;
    } else {
        for (int e = e0; e < E; ++e) {
            int p = pack[e];
            src_sorted[rowptr[dst[e]] + (p >> 17)] = p & 0x1FFFF;
        }
    }
}

// ---------------------------------------------------------------------------
// K5 v4: node-centric fused softmax-attention + bias + LN + ELU.
//     (r15/r16 passing version, byte-identical.)
// ---------------------------------------------------------------------------
__global__ __launch_bounds__(256) void node_kernel(
    const float4* __restrict__ fsq,      // fs as [N][16] float4 (8 bf16 each)
    const int* __restrict__ rowptr, const int* __restrict__ src_sorted,
    const float4* __restrict__ attn4,    // [32] float4
    const float4* __restrict__ obias4,
    const float4* __restrict__ lnw4,
    const float4* __restrict__ lnb4,
    float4* __restrict__ out4, int N)    // d_out as [N][32] float4
{
    int lane = threadIdx.x & 63;
    int es = lane >> 4;       // edge slot
    int g  = lane & 15;       // dim group: dims g*8 .. g*8+7
    int n = blockIdx.x * 4 + (threadIdx.x >> 6);
    if (n >= N) return;

    float4 fda = out4[(size_t)n * 32 + g * 2];
    float4 fdb = out4[(size_t)n * 32 + g * 2 + 1];
    float4 ava = attn4[g * 2];
    float4 avb = attn4[g * 2 + 1];
    float fd[8] = {fda.x, fda.y, fda.z, fda.w, fdb.x, fdb.y, fdb.z, fdb.w};
    float av[8] = {ava.x, ava.y, ava.z, ava.w, avb.x, avb.y, avb.z, avb.w};

    int beg = rowptr[n], end = rowptr[n + 1];
    float l = 0.f;
    float ac[8] = {0.f, 0.f, 0.f, 0.f, 0.f, 0.f, 0.f, 0.f};

    for (int j = beg; j < end; j += 4) {
        int idx = j + es;
        bool valid = idx < end;
        int s = src_sorted[valid ? idx : (end - 1)];
        float4 raw = fsq[(size_t)s * 16 + g];
        float a[8];
        unpack8(raw, a);
        float p = 0.f;
#pragma unroll
        for (int d = 0; d < 8; ++d) {
            float t = a[d] + fd[d];
            t = fmaxf(t, 0.2f * t);          // leaky_relu
            p += av[d] * t;
        }
        p += __shfl_xor(p, 1);               // head reduce (4 lanes/head)
        p += __shfl_xor(p, 2);
        float e = valid ? __expf(p) : 0.f;
        l += e;
#pragma unroll
        for (int d = 0; d < 8; ++d) ac[d] += e * a[d];
    }

    l += __shfl_xor(l, 16);
    l += __shfl_xor(l, 32);
#pragma unroll
    for (int d = 0; d < 8; ++d) {
        ac[d] += __shfl_xor(ac[d], 16);
        ac[d] += __shfl_xor(ac[d], 32);
    }

    float rl = (l > 0.f) ? (1.f / l) : 0.f;
    float4 oba = obias4[g * 2];
    float4 obb = obias4[g * 2 + 1];
    float ob[8] = {oba.x, oba.y, oba.z, oba.w, obb.x, obb.y, obb.z, obb.w};
    float h[8];
    float s1 = 0.f, s2 = 0.f;
#pragma unroll
    for (int d = 0; d < 8; ++d) {
        h[d] = ac[d] * rl + ob[d];
        s1 += h[d];
        s2 += h[d] * h[d];
    }
    s1 += __shfl_xor(s1, 1); s2 += __shfl_xor(s2, 1);
    s1 += __shfl_xor(s1, 2); s2 += __shfl_xor(s2, 2);
    s1 += __shfl_xor(s1, 4); s2 += __shfl_xor(s2, 4);
    s1 += __shfl_xor(s1, 8); s2 += __shfl_xor(s2, 8);

    float u = s1 * (1.f / NF);
    float var = s2 * (1.f / NF) - u * u;
    float rstd = rsqrtf(fmaxf(var, 0.f) + 1e-12f);
    float4 gwa = lnw4[g * 2], gwb = lnw4[g * 2 + 1];
    float4 gba = lnb4[g * 2], gbb = lnb4[g * 2 + 1];
    float gw[8] = {gwa.x, gwa.y, gwa.z, gwa.w, gwb.x, gwb.y, gwb.z, gwb.w};
    float gb[8] = {gba.x, gba.y, gba.z, gba.w, gbb.x, gbb.y, gbb.z, gbb.w};
    float z[8];
#pragma unroll
    for (int d = 0; d < 8; ++d) {
        float y = gw[d] * ((h[d] - u) * rstd) + gb[d];
        z[d] = (y > 0.f) ? y : (__expf(y) - 1.f);   // ELU alpha=1
    }
    if (es == 0) {
        out4[(size_t)n * 32 + g * 2]     = make_float4(z[0], z[1], z[2], z[3]);
        out4[(size_t)n * 32 + g * 2 + 1] = make_float4(z[4], z[5], z[6], z[7]);
    }
}

// ---------------------------------------------------------------------------
extern "C" void kernel_launch(void* const* d_in, const int* in_sizes, int n_in,
                              void* d_out, int out_size, void* d_ws, size_t ws_size,
                              hipStream_t stream)
{
    const float* x    = (const float*)d_in[0];
    const float* Wsrc = (const float*)d_in[1];
    const float* bsrc = (const float*)d_in[2];
    const float* Wdst = (const float*)d_in[3];
    const float* bdst = (const float*)d_in[4];
    const float4* attn4 = (const float4*)d_in[5];
    const float4* obias4= (const float4*)d_in[6];
    const float4* lnw4  = (const float4*)d_in[7];
    const float4* lnb4  = (const float4*)d_in[8];
    const int* src = (const int*)d_in[9];
    const int* dst = (const int*)d_in[10];
    int N = in_sizes[0] / NF;
    int E = in_sizes[9];
    int NB = (N + 255) / 256;   // 196 for N = 50000

    // workspace: cnt N | rowptr N+1 | state NB | pack E | srcs E | Wb | fs
    int* cnt = (int*)d_ws;                       // N
    int* rowptr = cnt + N;                       // N+1
    int* state = rowptr + (N + 1);               // NB
    int* pack = state + NB;                      // E
    int* srcs = pack + E;                        // E
    unsigned short* Wb = (unsigned short*)(srcs + E);    // [256][128] bf16
    unsigned short* fs = Wb + 256 * NF;          // [N][128] bf16

    int NGB = (N + 31) / 32;                     // 1563 gemm-tile blocks
    int GB  = (E + 255) / 256;                   // 3125 hist chunks
    if (GB < NGB) GB = NGB;

    prep_kernel<<<NB, 256, 0, stream>>>(Wsrc, Wdst, Wb, cnt, state, N, NB);
    gemm_hist_kernel<<<GB, 256, 0, stream>>>(
        x, Wb, bsrc, bdst, fs, (float*)d_out, src, dst, cnt, pack, N, E, NGB);
    scan_kernel<<<NB, 256, 0, stream>>>(cnt, rowptr, state, N, E);
    scatter_kernel<<<(E / 4 + 255) / 256, 256, 0, stream>>>(dst, pack, rowptr, srcs, E);
    node_kernel<<<(N + 3) / 4, 256, 0, stream>>>(
        (const float4*)fs, rowptr, srcs, attn4, obias4, lnw4, lnb4,
        (float4*)d_out, N);
}